// Round 15
// baseline (1014.505 us; speedup 1.0000x reference)
//
#include <hip/hip_runtime.h>
#include <hip/hip_bf16.h>
#include <hip/hip_fp16.h>
#include <math.h>

#define L_SEQ 2048
#define DM    2048
#define NH    16
#define DH    128
#define HVD   256
#define NPROJ 12320
#define QKVW  8192
#define GW    4128

#define NTILE_N 97
#define KSTEPS  64

typedef _Float16 v8h __attribute__((ext_vector_type(8)));
typedef float f32x4 __attribute__((ext_vector_type(4)));

__device__ __forceinline__ void gload_lds16(const void* g, void* l) {
  __builtin_amdgcn_global_load_lds((const __attribute__((address_space(1))) void*)g,
                                   (__attribute__((address_space(3))) void*)l, 16, 0, 0);
}

__device__ __forceinline__ void splitw(float x, unsigned short& h, unsigned short& l) {
  _Float16 hh = (_Float16)x;
  _Float16 ll = (_Float16)(x - (float)hh);
  h = *(unsigned short*)&hh;
  l = *(unsigned short*)&ll;
}
__device__ __forceinline__ float h2f(unsigned short u) {
  return (float)(*(_Float16*)&u);
}

#define MFMA3(acc, ah, al, bh_, bl_)                                          \
  acc = __builtin_amdgcn_mfma_f32_16x16x32_f16(ah, bh_, acc, 0, 0, 0);        \
  acc = __builtin_amdgcn_mfma_f32_16x16x32_f16(ah, bl_, acc, 0, 0, 0);        \
  acc = __builtin_amdgcn_mfma_f32_16x16x32_f16(al, bh_, acc, 0, 0, 0);

// ---------------- pack A: hidden(4096x2048) f32 -> fp16 hi/lo, x16 ----------------
__global__ __launch_bounds__(256) void pack_A_k(const float* __restrict__ H, _Float16* __restrict__ Ap) {
  const int mtile = blockIdx.x >> 6, kstep = blockIdx.x & 63;
  const size_t base = (size_t)blockIdx.x * 2 * 4096;
#pragma unroll
  for (int it = 0; it < 2; ++it) {
    int s = threadIdx.x + it * 256;
    int g = s >> 7, r = s & 127;
    const float* src = H + ((size_t)(mtile * 128 + r)) * 2048 + kstep * 32 + g * 8;
    float4 x0 = *(const float4*)src;
    float4 x1 = *(const float4*)(src + 4);
    float xs[8] = {x0.x, x0.y, x0.z, x0.w, x1.x, x1.y, x1.z, x1.w};
    v8h hi, lo;
#pragma unroll
    for (int j = 0; j < 8; ++j) {
      float v = xs[j] * 16.f;
      _Float16 h = (_Float16)v;
      hi[j] = h;
      lo[j] = (_Float16)(v - (float)h);
    }
    *(v8h*)(Ap + base + g * 1024 + r * 8) = hi;
    *(v8h*)(Ap + base + 4096 + g * 1024 + r * 8) = lo;
  }
}

// ---------------- pack B: W(2048x12320) f32 -> fp16 hi/lo, x1024 ----------------
__global__ __launch_bounds__(256) void pack_B_k(const float* __restrict__ W, _Float16* __restrict__ Bp) {
  const int ntile = blockIdx.x >> 6, kstep = blockIdx.x & 63;
  const size_t base = (size_t)blockIdx.x * 2 * 4096;
#pragma unroll
  for (int it = 0; it < 2; ++it) {
    int s = threadIdx.x + it * 256;
    int g = s >> 7, col = s & 127;
    int n = ntile * 128 + col;
    v8h hi, lo;
#pragma unroll
    for (int j = 0; j < 8; ++j) {
      int k = kstep * 32 + g * 8 + j;
      float v = (n < NPROJ) ? W[(size_t)k * NPROJ + n] * 1024.f : 0.f;
      _Float16 h = (_Float16)v;
      hi[j] = h;
      lo[j] = (_Float16)(v - (float)h);
    }
    *(v8h*)(Bp + base + g * 1024 + col * 8) = hi;
    *(v8h*)(Bp + base + 4096 + g * 1024 + col * 8) = lo;
  }
}

// ---------------- 256x256 split-fp16 MFMA GEMM: R11-exact (8 waves, 1 barrier/K-step) ----------------
__global__ __launch_bounds__(512, 2) void gemm256_k(const _Float16* __restrict__ Ap,
                                                    const _Float16* __restrict__ Bp,
                                                    float* __restrict__ Cq,
                                                    float* __restrict__ Cg) {
  __shared__ _Float16 lds[2][32768];
  const int tid = threadIdx.x;
  const int supM = blockIdx.x & 15;
  const int supN = blockIdx.x >> 4;          // 0..47
  const int w = tid >> 6, lane = tid & 63;
  const int wm = w >> 2, wn = w & 3;
  const int lr = lane & 15, g16 = lane >> 4;

  f32x4 acc[8][4];
#pragma unroll
  for (int i = 0; i < 8; ++i)
#pragma unroll
    for (int j = 0; j < 4; ++j) acc[i][j] = (f32x4){0.f, 0.f, 0.f, 0.f};

  const size_t Ab0 = (size_t)(2 * supM) * KSTEPS * 8192;
  const size_t Ab1 = Ab0 + (size_t)KSTEPS * 8192;
  const size_t Bb0 = (size_t)(2 * supN) * KSTEPS * 8192;
  const size_t Bb1 = Bb0 + (size_t)KSTEPS * 8192;
  const int so = tid * 8;

#define STG(KS, BUF)                                                           \
  {                                                                            \
    const size_t ko = (size_t)(KS) * 8192;                                     \
    gload_lds16(Ap + Ab0 + ko + so,        &lds[BUF][so]);                     \
    gload_lds16(Ap + Ab0 + ko + so + 4096, &lds[BUF][so + 4096]);              \
    gload_lds16(Ap + Ab1 + ko + so,        &lds[BUF][8192 + so]);              \
    gload_lds16(Ap + Ab1 + ko + so + 4096, &lds[BUF][8192 + so + 4096]);       \
    gload_lds16(Bp + Bb0 + ko + so,        &lds[BUF][16384 + so]);             \
    gload_lds16(Bp + Bb0 + ko + so + 4096, &lds[BUF][16384 + so + 4096]);      \
    gload_lds16(Bp + Bb1 + ko + so,        &lds[BUF][24576 + so]);             \
    gload_lds16(Bp + Bb1 + ko + so + 4096, &lds[BUF][24576 + so + 4096]);      \
  }

  STG(0, 0);
  asm volatile("s_waitcnt vmcnt(0)" ::: "memory");
  __builtin_amdgcn_sched_barrier(0);
  __builtin_amdgcn_s_barrier();
  __builtin_amdgcn_sched_barrier(0);

  const int aoffB = wm * 8192 + lr * 8 + g16 * 1024;
  const int boffB = 16384 + (wn >> 1) * 8192 + ((wn & 1) * 64 + lr) * 8 + g16 * 1024;

  for (int kstep = 0; kstep < KSTEPS; ++kstep) {
    const int p = kstep & 1;
    if (kstep + 1 < KSTEPS) STG(kstep + 1, p ^ 1);

    v8h ah[8], al[8];
#pragma unroll
    for (int mb = 0; mb < 8; ++mb) {
      ah[mb] = *(const v8h*)&lds[p][aoffB + mb * 128];
      al[mb] = *(const v8h*)&lds[p][aoffB + mb * 128 + 4096];
    }
#pragma unroll
    for (int nt = 0; nt < 4; ++nt) {
      v8h bh = *(const v8h*)&lds[p][boffB + nt * 128];
      v8h bl = *(const v8h*)&lds[p][boffB + nt * 128 + 4096];
#pragma unroll
      for (int mb = 0; mb < 8; ++mb) {
        MFMA3(acc[mb][nt], ah[mb], al[mb], bh, bl);
      }
    }
    asm volatile("s_waitcnt vmcnt(0)" ::: "memory");
    __builtin_amdgcn_sched_barrier(0);
    __builtin_amdgcn_s_barrier();
    __builtin_amdgcn_sched_barrier(0);
  }
#undef STG

  const float sc = 1.f / 16384.f;
#pragma unroll
  for (int mb = 0; mb < 8; ++mb) {
#pragma unroll
    for (int nt = 0; nt < 4; ++nt) {
      int col = supN * 256 + wn * 64 + nt * 16 + lr;
#pragma unroll
      for (int r = 0; r < 4; ++r) {
        int row = supM * 256 + wm * 128 + mb * 16 + g16 * 4 + r;
        float v = acc[mb][nt][r] * sc;
        if (col < QKVW) Cq[(size_t)row * QKVW + col] = v;
        else            Cg[(size_t)row * GW + (col - QKVW)] = v;
      }
    }
  }
}

// ---------------- tail: b/A columns (ntile 96, first 32 cols) split-K partials ----------------
__global__ __launch_bounds__(256) void tail_k(const _Float16* __restrict__ Ap,
                                              const _Float16* __restrict__ Bp,
                                              float* __restrict__ partial) {
  __shared__ _Float16 lds[16384];
  const int bid = blockIdx.x;
  const int kseg = bid >> 5, mtile = bid & 31;
  const int tid = threadIdx.x;
  const int wid = tid >> 6, lane = tid & 63, lr = lane & 15, g16 = lane >> 4;

  f32x4 acc[2][2];
#pragma unroll
  for (int i = 0; i < 2; ++i)
#pragma unroll
    for (int j = 0; j < 2; ++j) acc[i][j] = (f32x4){0.f, 0.f, 0.f, 0.f};

  const _Float16* Asrc = Ap + ((size_t)(mtile * KSTEPS) * 2) * 4096 + tid * 8;
  const _Float16* Bsrc = Bp + ((size_t)(96 * KSTEPS) * 2) * 4096 + tid * 8;

  for (int ks = kseg * 16; ks < kseg * 16 + 16; ++ks) {
    __syncthreads();
#pragma unroll
    for (int r = 0; r < 4; ++r) {
      gload_lds16(Asrc + (size_t)ks * 8192 + r * 2048, &lds[r * 2048 + tid * 8]);
      gload_lds16(Bsrc + (size_t)ks * 8192 + r * 2048, &lds[8192 + r * 2048 + tid * 8]);
    }
    __syncthreads();
    const int abase = g16 * 1024;
#pragma unroll
    for (int fm = 0; fm < 2; ++fm) {
      int row = wid * 32 + fm * 16 + lr;
      v8h ah = *(const v8h*)&lds[abase + row * 8];
      v8h al = *(const v8h*)&lds[4096 + abase + row * 8];
#pragma unroll
      for (int fn = 0; fn < 2; ++fn) {
        int col = fn * 16 + lr;
        v8h bh = *(const v8h*)&lds[8192 + abase + col * 8];
        v8h bl = *(const v8h*)&lds[12288 + abase + col * 8];
        MFMA3(acc[fm][fn], ah, al, bh, bl);
      }
    }
  }

  const float sc = 1.f / 16384.f;
#pragma unroll
  for (int fm = 0; fm < 2; ++fm)
#pragma unroll
    for (int fn = 0; fn < 2; ++fn) {
      int col = fn * 16 + lr;
#pragma unroll
      for (int r = 0; r < 4; ++r) {
        int row = mtile * 128 + wid * 32 + fm * 16 + g16 * 4 + r;
        partial[((size_t)kseg * 4096 + row) * 32 + col] = acc[fm][fn][r] * sc;
      }
    }
}

// ------------- conv+silu+l2norm for q/k -> PRE-SPLIT fp16 hi/lo, pre-swizzled table layout -------------
__global__ __launch_bounds__(64) void conv_qk_k(
    const float* __restrict__ projQKV, const float* __restrict__ Wc,
    _Float16* __restrict__ qh, _Float16* __restrict__ ql,
    _Float16* __restrict__ kh, _Float16* __restrict__ kl)
{
  const int b = blockIdx.z, hg = blockIdx.y, tc = blockIdx.x;
  const int lane = threadIdx.x;
  const int ch = hg * 128 + lane * 2;
  float4 Wa = *(const float4*)(Wc + (size_t)ch * 4);
  float4 Wb = *(const float4*)(Wc + (size_t)ch * 4 + 4);
  const int t0 = tc * 64;
  const float* P = projQKV + (size_t)b * L_SEQ * QKVW + ch;
  float2 w0 = make_float2(0.f, 0.f), w1 = w0, w2 = w0;
  if (t0 >= 3) w0 = *(const float2*)(P + (size_t)(t0 - 3) * QKVW);
  if (t0 >= 2) w1 = *(const float2*)(P + (size_t)(t0 - 2) * QKVW);
  if (t0 >= 1) w2 = *(const float2*)(P + (size_t)(t0 - 1) * QKVW);
  const bool isq = hg < 16;
  const int h = isq ? hg : hg - 16;
  _Float16* dh = (isq ? qh : kh) + (((size_t)b * NH + h) * L_SEQ) * 128;
  _Float16* dl = (isq ? ql : kl) + (((size_t)b * NH + h) * L_SEQ) * 128;
  const float sc = (isq ? 0.08838834764831845f : 1.f) * 1024.f;
  for (int t = t0; t < t0 + 64; ++t) {
    float2 x = *(const float2*)(P + (size_t)t * QKVW);
    float y0 = w0.x * Wa.x + w1.x * Wa.y + w2.x * Wa.z + x.x * Wa.w;
    float y1 = w0.y * Wb.x + w1.y * Wb.y + w2.y * Wb.z + x.y * Wb.w;
    w0 = w1; w1 = w2; w2 = x;
    y0 = y0 / (1.f + expf(-y0));
    y1 = y1 / (1.f + expf(-y1));
    float ss = y0 * y0 + y1 * y1;
#pragma unroll
    for (int off = 1; off < 64; off <<= 1) ss += __shfl_xor(ss, off);
    float nrm = sc / sqrtf(ss + 1e-6f);
    unsigned short h0, l0, h1, l1;
    splitw(y0 * nrm, h0, l0);
    splitw(y1 * nrm, h1, l1);
    int idx = t * 128 + ((lane * 2) ^ ((t & 7) << 3));
    *(unsigned int*)&dh[idx] = (unsigned int)h0 | ((unsigned int)h1 << 16);
    *(unsigned int*)&dl[idx] = (unsigned int)l0 | ((unsigned int)l1 << 16);
  }
}

// ------------- conv+silu for v: elementwise, float4 per thread -------------
__global__ __launch_bounds__(256) void conv_v_k(
    const float* __restrict__ projQKV, const float* __restrict__ Wc,
    float* __restrict__ vn)
{
  const int b = blockIdx.z, cg = blockIdx.y, tc = blockIdx.x;
  const int vc = (cg * 256 + threadIdx.x) * 4;
  const int ch = 4096 + vc;
  float4 Wv0 = *(const float4*)(Wc + (size_t)ch * 4);
  float4 Wv1 = *(const float4*)(Wc + (size_t)ch * 4 + 4);
  float4 Wv2 = *(const float4*)(Wc + (size_t)ch * 4 + 8);
  float4 Wv3 = *(const float4*)(Wc + (size_t)ch * 4 + 12);
  const int t0 = tc * 64;
  const float* P = projQKV + (size_t)b * L_SEQ * QKVW + ch;
  float4 w0 = make_float4(0.f, 0.f, 0.f, 0.f), w1 = w0, w2 = w0;
  if (t0 >= 3) w0 = *(const float4*)(P + (size_t)(t0 - 3) * QKVW);
  if (t0 >= 2) w1 = *(const float4*)(P + (size_t)(t0 - 2) * QKVW);
  if (t0 >= 1) w2 = *(const float4*)(P + (size_t)(t0 - 1) * QKVW);
  const int h = vc >> 8, vcol = vc & 255;
  float* dst = vn + (((size_t)b * NH + h) * L_SEQ) * HVD + vcol;
  for (int t = t0; t < t0 + 64; ++t) {
    float4 x = *(const float4*)(P + (size_t)t * QKVW);
    float4 y;
    y.x = w0.x * Wv0.x + w1.x * Wv0.y + w2.x * Wv0.z + x.x * Wv0.w;
    y.y = w0.y * Wv1.x + w1.y * Wv1.y + w2.y * Wv1.z + x.y * Wv1.w;
    y.z = w0.z * Wv2.x + w1.z * Wv2.y + w2.z * Wv2.z + x.z * Wv2.w;
    y.w = w0.w * Wv3.x + w1.w * Wv3.y + w2.w * Wv3.z + x.w * Wv3.w;
    w0 = w1; w1 = w2; w2 = x;
    y.x = y.x / (1.f + expf(-y.x));
    y.y = y.y / (1.f + expf(-y.y));
    y.z = y.z / (1.f + expf(-y.z));
    y.w = y.w / (1.f + expf(-y.w));
    *(float4*)(dst + (size_t)t * HVD) = y;
  }
}

// ------------- beta/g from split-K partials -------------
__global__ __launch_bounds__(256) void beta_g_k(
    const float* __restrict__ partial, const float* __restrict__ A_log,
    const float* __restrict__ dt_bias, float* __restrict__ beta, float* __restrict__ g_out)
{
  int idx = blockIdx.x * 256 + threadIdx.x;
  if (idx >= 2 * NH * L_SEQ) return;
  int t = idx & (L_SEQ - 1);
  int h = (idx >> 11) & (NH - 1);
  int b = idx >> 15;
  size_t row = (size_t)(b * L_SEQ + t);
  float bv = 0.f, av = 0.f;
#pragma unroll
  for (int s = 0; s < 4; ++s) {
    bv += partial[((size_t)s * 4096 + row) * 32 + h];
    av += partial[((size_t)s * 4096 + row) * 32 + 16 + h];
  }
  float be = 1.f / (1.f + expf(-bv));
  float xx = av + dt_bias[h];
  float sp = (xx > 20.f) ? xx : log1pf(expf(xx));
  float g = -expf(A_log[h]) * sp;
  beta[idx] = be;
  g_out[idx] = g;
}

// ------------- Phase 1 (fused): T=(I+A)^-1, Hq, KT, coef — gload-staged pre-split q/k -------------
__global__ __launch_bounds__(256) void p1_k(
    const _Float16* __restrict__ kh_g, const _Float16* __restrict__ kl_g,
    const _Float16* __restrict__ qh_g, const _Float16* __restrict__ ql_g,
    const float* __restrict__ g_arr, const float* __restrict__ beta_arr,
    _Float16* __restrict__ Tg_h, _Float16* __restrict__ Tg_l,
    _Float16* __restrict__ Hg_h, _Float16* __restrict__ Hg_l,
    _Float16* __restrict__ KTg_h, _Float16* __restrict__ KTg_l,
    float* __restrict__ coefG)
{
  __shared__ _Float16 Kh[8192], Kl[8192];
  __shared__ _Float16 QS[16384];
  __shared__ float lc[64], be[64], kw[64];
  _Float16* Qh = QS;
  _Float16* Ql = QS + 8192;
  float* Am = (float*)QS;
  float* Tm = Am + 4096;
  const int cid = blockIdx.x, bh = cid >> 5, ch = cid & 31, t0 = ch * 64;
  const int tid = threadIdx.x, w = tid >> 6, lane = tid & 63, lr = lane & 15, g16 = lane >> 4;

  const size_t gb = ((size_t)bh * 2048 + t0) * 128;
#pragma unroll
  for (int l = 0; l < 4; ++l) {
    int i = (tid + l * 256) * 8;
    gload_lds16(kh_g + gb + i, &Kh[i]);
    gload_lds16(kl_g + gb + i, &Kl[i]);
    gload_lds16(qh_g + gb + i, &Qh[i]);
    gload_lds16(ql_g + gb + i, &Ql[i]);
  }
  if (tid < 64) {
    float x = g_arr[(size_t)bh * 2048 + t0 + tid];
#pragma unroll
    for (int off = 1; off < 64; off <<= 1) { float y = __shfl_up(x, off); if (tid >= off) x += y; }
    lc[tid] = x;
    float x63 = __shfl(x, 63);
    float b_ = beta_arr[(size_t)bh * 2048 + t0 + tid];
    be[tid] = b_;
    kw[tid] = expf(x63 - x);
    float ca = expf(x);
    coefG[(size_t)cid * 192 + tid] = ca;
    coefG[(size_t)cid * 192 + 64 + tid] = b_;
    coefG[(size_t)cid * 192 + 128 + tid] = b_ * ca;
  }
  __syncthreads();
  const float ds20 = 1.f / 1048576.f;
  const int arow = w * 16 + lr, swa = (arow & 7) << 3;
  f32x4 gacc[4];
  for (int nt = 0; nt < 4; ++nt) {
    f32x4 acc = (f32x4){0.f, 0.f, 0.f, 0.f};
    int nrow = nt * 16 + lr, swn = (nrow & 7) << 3;
#pragma unroll
    for (int ks = 0; ks < 4; ++ks) {
      int c = ks * 32 + g16 * 8;
      v8h ah = *(const v8h*)&Kh[arow * 128 + (c ^ swa)];
      v8h al = *(const v8h*)&Kl[arow * 128 + (c ^ swa)];
      v8h bhh = *(const v8h*)&Kh[nrow * 128 + (c ^ swn)];
      v8h bll = *(const v8h*)&Kl[nrow * 128 + (c ^ swn)];
      MFMA3(acc, ah, al, bhh, bll);
    }
    gacc[nt] = acc;
  }
  for (int nt = 0; nt < 4; ++nt) {
    f32x4 acc = (f32x4){0.f, 0.f, 0.f, 0.f};
    int nrow = nt * 16 + lr, swn = (nrow & 7) << 3;
#pragma unroll
    for (int ks = 0; ks < 4; ++ks) {
      int c = ks * 32 + g16 * 8;
      v8h ah = *(const v8h*)&Qh[arow * 128 + (c ^ swa)];
      v8h al = *(const v8h*)&Ql[arow * 128 + (c ^ swa)];
      v8h bhh = *(const v8h*)&Kh[nrow * 128 + (c ^ swn)];
      v8h bll = *(const v8h*)&Kl[nrow * 128 + (c ^ swn)];
      MFMA3(acc, ah, al, bhh, bll);
    }
    int s_ = nt * 16 + lr;
#pragma unroll
    for (int r = 0; r < 4; ++r) {
      int t = w * 16 + g16 * 4 + r;
      float hv = (s_ <= t) ? acc[r] * ds20 * expf(lc[t] - lc[s_]) : 0.f;
      unsigned short hh, ll; splitw(hv * 16384.f, hh, ll);
      size_t go = (size_t)cid * 4096 + t * 64 + (s_ ^ ((t & 7) << 3));
      *(unsigned short*)&Hg_h[go] = hh;
      *(unsigned short*)&Hg_l[go] = ll;
    }
  }
  __syncthreads();
  for (int nt = 0; nt < 4; ++nt) {
    int s_ = nt * 16 + lr;
#pragma unroll
    for (int r = 0; r < 4; ++r) {
      int t = w * 16 + g16 * 4 + r;
      float av = (s_ < t) ? gacc[nt][r] * ds20 * be[t] * expf(lc[t] - lc[s_]) : 0.f;
      Am[t * 64 + s_] = av;
    }
  }
#pragma unroll
  for (int l = 0; l < 16; ++l) { int s2 = tid + l * 256; Tm[s2] = ((s2 >> 6) == (s2 & 63)) ? 1.f : 0.f; }
  for (int s = tid; s < 8192; s += 256) {
    int feat = s >> 6, t = s & 63;
    int ki = t * 128 + (feat ^ ((t & 7) << 3));
    float kvv = ((float)Kh[ki] + (float)Kl[ki]) * kw[t];
    unsigned short hh, ll; splitw(kvv, hh, ll);
    size_t go = (size_t)cid * 8192 + feat * 64 + (t ^ ((feat & 7) << 3));
    *(unsigned short*)&KTg_h[go] = hh;
    *(unsigned short*)&KTg_l[go] = ll;
  }
  __syncthreads();
  if (w == 0) {
    int j = lane;
    for (int t = 1; t < 64; ++t) {
      float sum = 0.f;
      for (int s = 0; s < t; ++s) sum = fmaf(Am[t * 64 + s], Tm[s * 64 + j], sum);
      Tm[t * 64 + j] = ((j == t) ? 1.f : 0.f) - sum;
    }
  }
  __syncthreads();
#pragma unroll
  for (int l = 0; l < 16; ++l) {
    int s2 = tid + l * 256;
    int t = s2 >> 6, sc_ = s2 & 63;
    unsigned short hh, ll; splitw(Tm[s2] * 256.f, hh, ll);
    size_t go = (size_t)cid * 4096 + t * 64 + (sc_ ^ ((t & 7) << 3));
    *(unsigned short*)&Tg_h[go] = hh;
    *(unsigned short*)&Tg_l[go] = ll;
  }
}

// ------------- Phase 2: chunk scan with DIRECT-GLOBAL table fragments (48KB LDS, 3 barriers/chunk) -------------
__global__ __launch_bounds__(256) void p2_k(
    const _Float16* __restrict__ qh_g, const _Float16* __restrict__ ql_g,
    const _Float16* __restrict__ kh_g, const _Float16* __restrict__ kl_g,
    const float* __restrict__ vn, const float* __restrict__ projGate,
    const _Float16* __restrict__ Tg_h, const _Float16* __restrict__ Tg_l,
    const _Float16* __restrict__ Hg_h, const _Float16* __restrict__ Hg_l,
    const _Float16* __restrict__ KTg_h, const _Float16* __restrict__ KTg_l,
    const float* __restrict__ coefG, float* __restrict__ out)
{
  __shared__ _Float16 St_h[4096], St_l[4096];
  __shared__ _Float16 BT_h[4096], BT_l[4096];
  __shared__ _Float16 UT_h[4096], UT_l[4096];

  const int blk = blockIdx.x;
  const int vb = blk >> 5, bh = blk & 31;   // all vb of a bh on same XCD (blk%8 = bh%8)
  const int b = bh >> 4, h = bh & 15, v0 = vb * 32;
  const int tid = threadIdx.x, w = tid >> 6, lane = tid & 63, lr = lane & 15, g16 = lane >> 4;

#pragma unroll
  for (int l = 0; l < 8; ++l) { ((unsigned int*)St_h)[tid + l * 256] = 0u; }
#pragma unroll
  for (int l = 0; l < 8; ++l) { ((unsigned int*)St_l)[tid + l * 256] = 0u; }
  __syncthreads();

  const float* gp = projGate + ((size_t)b * 2048) * GW + h * 256 + v0;
  const float i2_16 = 1.f / 65536.f;
  const float i2_20 = 1.f / 1048576.f;
  const float uscale = 1.f / 256.f;
  const float sscale = 64.f / 65536.f;
  const int arow = w * 16 + lr, swa = (arow & 7) << 3;
  const int tb = w * 16 + g16 * 4;

  for (int ch = 0; ch < 32; ++ch) {
    const int cid = bh * 32 + ch, t0 = ch * 64;
    const size_t gb = ((size_t)bh * 2048 + t0) * 128;
    const _Float16* Tb = Tg_h + (size_t)cid * 4096;
    const _Float16* Tbl = Tg_l + (size_t)cid * 4096;
    const _Float16* Hb = Hg_h + (size_t)cid * 4096;
    const _Float16* Hbl = Hg_l + (size_t)cid * 4096;
    const _Float16* KTb = KTg_h + (size_t)cid * 8192;
    const _Float16* KTbl = KTg_l + (size_t)cid * 8192;
    const float* cfp = coefG + (size_t)cid * 192;
    const float cc = cfp[63];
    float4 cav = *(const float4*)&cfp[w * 16 + g16 * 4];
    float4 cb1v = *(const float4*)&cfp[64 + w * 16 + g16 * 4];
    float4 cb2v = *(const float4*)&cfp[128 + w * 16 + g16 * 4];
    float Vv[2][4];
#pragma unroll
    for (int nt = 0; nt < 2; ++nt)
#pragma unroll
      for (int r = 0; r < 4; ++r)
        Vv[nt][r] = vn[((size_t)bh * 2048 + t0 + w * 16 + g16 * 4 + r) * 256 + v0 + nt * 16 + lr];

    // ---- QS0 -> Oacc (Q frags direct from global) ----
    f32x4 Oacc[2];
    {
      for (int nt = 0; nt < 2; ++nt) {
        f32x4 acc = (f32x4){0.f, 0.f, 0.f, 0.f};
        const int n = nt * 16 + lr, swn = (n & 7) << 3;
#pragma unroll
        for (int ks = 0; ks < 4; ++ks) {
          int c = ks * 32 + g16 * 8;
          v8h ah = *(const v8h*)(qh_g + gb + arow * 128 + (c ^ swa));
          v8h al = *(const v8h*)(ql_g + gb + arow * 128 + (c ^ swa));
          v8h bhh = *(const v8h*)&St_h[n * 128 + (c ^ swn)];
          v8h bll = *(const v8h*)&St_l[n * 128 + (c ^ swn)];
          MFMA3(acc, ah, al, bhh, bll);
        }
        Oacc[nt] = acc;
      }
#pragma unroll
      for (int nt = 0; nt < 2; ++nt) {
        Oacc[nt][0] *= cav.x * 16.f; Oacc[nt][1] *= cav.y * 16.f;
        Oacc[nt][2] *= cav.z * 16.f; Oacc[nt][3] *= cav.w * 16.f;
      }
    }
    // ---- KS0 -> B regs (K frags direct from global) ----
    ushort4 pBh[2], pBl[2];
    {
      float cb1a[4] = {cb1v.x, cb1v.y, cb1v.z, cb1v.w};
      float cb2a[4] = {cb2v.x, cb2v.y, cb2v.z, cb2v.w};
      for (int nt = 0; nt < 2; ++nt) {
        f32x4 acc = (f32x4){0.f, 0.f, 0.f, 0.f};
        const int n = nt * 16 + lr, swn = (n & 7) << 3;
#pragma unroll
        for (int ks = 0; ks < 4; ++ks) {
          int c = ks * 32 + g16 * 8;
          v8h ah = *(const v8h*)(kh_g + gb + arow * 128 + (c ^ swa));
          v8h al = *(const v8h*)(kl_g + gb + arow * 128 + (c ^ swa));
          v8h bhh = *(const v8h*)&St_h[n * 128 + (c ^ swn)];
          v8h bll = *(const v8h*)&St_l[n * 128 + (c ^ swn)];
          MFMA3(acc, ah, al, bhh, bll);
        }
        unsigned short* ph = (unsigned short*)&pBh[nt];
        unsigned short* pl = (unsigned short*)&pBl[nt];
#pragma unroll
        for (int r = 0; r < 4; ++r) {
          float kv = acc[r] * i2_16;
          float Bv = cb1a[r] * Vv[nt][r] - cb2a[r] * kv;
          splitw(Bv * 64.f, ph[r], pl[r]);
        }
      }
      // write BT (transposed; region last read before previous chunk's 2nd barrier)
      for (int nt = 0; nt < 2; ++nt) {
        const int n = nt * 16 + lr, swn = (n & 7) << 3;
        int ad = n * 64 + (tb ^ swn);
        *(ushort4*)&BT_h[ad] = pBh[nt];
        *(ushort4*)&BT_l[ad] = pBl[nt];
      }
    }
    __syncthreads();   // (1) BT visible
    // ---- UT = T @ BT (T frags direct from global) ----
    {
      for (int nt = 0; nt < 2; ++nt) {
        f32x4 acc = (f32x4){0.f, 0.f, 0.f, 0.f};
        const int n = nt * 16 + lr, swn = (n & 7) << 3;
#pragma unroll
        for (int ks = 0; ks < 2; ++ks) {
          int c = ks * 32 + g16 * 8;
          v8h ah = *(const v8h*)(Tb + arow * 64 + (c ^ swa));
          v8h al = *(const v8h*)(Tbl + arow * 64 + (c ^ swa));
          v8h bhh = *(const v8h*)&BT_h[n * 64 + (c ^ swn)];
          v8h bll = *(const v8h*)&BT_l[n * 64 + (c ^ swn)];
          MFMA3(acc, ah, al, bhh, bll);
        }
        ushort4 H, L;
        unsigned short* ph = (unsigned short*)&H;
        unsigned short* pl = (unsigned short*)&L;
#pragma unroll
        for (int r = 0; r < 4; ++r) splitw(acc[r] * uscale, ph[r], pl[r]);
        int ad = n * 64 + (tb ^ swn);
        *(ushort4*)&UT_h[ad] = H;
        *(ushort4*)&UT_l[ad] = L;
      }
    }
    __syncthreads();   // (2) UT visible
    // ---- O += Hq @ UT ; write out ; S' = cc*S + KT @ UT ----
    {
      for (int nt = 0; nt < 2; ++nt) {
        const int n = nt * 16 + lr, swn = (n & 7) << 3;
#pragma unroll
        for (int ks = 0; ks < 2; ++ks) {
          int c = ks * 32 + g16 * 8;
          v8h ah = *(const v8h*)(Hb + arow * 64 + (c ^ swa));
          v8h al = *(const v8h*)(Hbl + arow * 64 + (c ^ swa));
          v8h bhh = *(const v8h*)&UT_h[n * 64 + (c ^ swn)];
          v8h bll = *(const v8h*)&UT_l[n * 64 + (c ^ swn)];
          MFMA3(Oacc[nt], ah, al, bhh, bll);
        }
      }
      for (int nt = 0; nt < 2; ++nt) {
        const int n = nt * 16 + lr;
#pragma unroll
        for (int r = 0; r < 4; ++r) {
          int t = t0 + w * 16 + g16 * 4 + r;
          float Ov = Oacc[nt][r] * i2_20;
          float gv = gp[(size_t)t * GW + n];
          out[((size_t)b * 2048 + t) * 4096 + h * 256 + v0 + n] = Ov * (gv / (1.f + expf(-gv)));
        }
      }
      const float cc1024 = cc * 1024.f;
#pragma unroll
      for (int m2 = w * 2; m2 < w * 2 + 2; ++m2) {
        const int ar2 = m2 * 16 + lr, swa2 = (ar2 & 7) << 3;
        const int fb = m2 * 16 + g16 * 4;
        for (int nt = 0; nt < 2; ++nt) {
          const int n = nt * 16 + lr, swn = (n & 7) << 3;
          int sad = n * 128 + (fb ^ swn);
          ushort4 sh4 = *(ushort4*)&St_h[sad];
          ushort4 sl4 = *(ushort4*)&St_l[sad];
          f32x4 acc;
          acc[0] = cc1024 * (h2f(sh4.x) + h2f(sl4.x));
          acc[1] = cc1024 * (h2f(sh4.y) + h2f(sl4.y));
          acc[2] = cc1024 * (h2f(sh4.z) + h2f(sl4.z));
          acc[3] = cc1024 * (h2f(sh4.w) + h2f(sl4.w));
#pragma unroll
          for (int ks = 0; ks < 2; ++ks) {
            int c = ks * 32 + g16 * 8;
            v8h ah = *(const v8h*)(KTb + ar2 * 64 + (c ^ swa2));
            v8h al = *(const v8h*)(KTbl + ar2 * 64 + (c ^ swa2));
            v8h bhh = *(const v8h*)&UT_h[n * 64 + (c ^ swn)];
            v8h bll = *(const v8h*)&UT_l[n * 64 + (c ^ swn)];
            MFMA3(acc, ah, al, bhh, bll);
          }
          ushort4 H, L;
          unsigned short* ph = (unsigned short*)&H;
          unsigned short* pl = (unsigned short*)&L;
#pragma unroll
          for (int r = 0; r < 4; ++r) splitw(acc[r] * sscale, ph[r], pl[r]);
          *(ushort4*)&St_h[sad] = H;
          *(ushort4*)&St_l[sad] = L;
        }
      }
    }
    __syncthreads();   // (3) St visible; BT/UT safe for next chunk
  }
}

extern "C" void kernel_launch(void* const* d_in, const int* in_sizes, int n_in,
                              void* d_out, int out_size, void* d_ws, size_t ws_size,
                              hipStream_t stream) {
  const float* hidden  = (const float*)d_in[0];
  const float* W       = (const float*)d_in[1];
  const float* Wc      = (const float*)d_in[2];
  const float* A_log   = (const float*)d_in[3];
  const float* dt_bias = (const float*)d_in[4];
  float* out = (float*)d_out;

  char* ws = (char*)d_ws;
  _Float16* Ap = (_Float16*)ws;
  _Float16* Bp = (_Float16*)(ws + (size_t)33554432);
  float* partial = (float*)(ws + (size_t)33554432);        // dead Bp tiles 0-1; consumed by beta_g before conv
  _Float16* qh = (_Float16*)ws;
  _Float16* ql = (_Float16*)(ws + (size_t)16777216);
  _Float16* kh = (_Float16*)(ws + (size_t)33554432);
  _Float16* kl = (_Float16*)(ws + (size_t)50331648);
  float* vn    = (float*)(ws + (size_t)67108864);
  float* g_arr = (float*)(ws + (size_t)134217728);
  float* beta  = (float*)(ws + (size_t)134479872);
  float* projQKV = (float*)(ws + (size_t)135266304);
  char*  tb0 = ws + (size_t)135266304;
  _Float16* Tg_h  = (_Float16*)tb0;
  _Float16* Tg_l  = (_Float16*)(tb0 + (size_t)8388608);
  _Float16* Hg_h  = (_Float16*)(tb0 + (size_t)16777216);
  _Float16* Hg_l  = (_Float16*)(tb0 + (size_t)25165824);
  _Float16* KTg_h = (_Float16*)(tb0 + (size_t)33554432);
  _Float16* KTg_l = (_Float16*)(tb0 + (size_t)50331648);
  float*    coefG = (float*)   (tb0 + (size_t)67108864);
  float* projGate = (float*)(ws + (size_t)269484032);

  pack_A_k<<<32 * KSTEPS, 256, 0, stream>>>(hidden, Ap);
  pack_B_k<<<NTILE_N * KSTEPS, 256, 0, stream>>>(W, Bp);
  gemm256_k<<<768, 512, 0, stream>>>(Ap, Bp, projQKV, projGate);
  tail_k<<<128, 256, 0, stream>>>(Ap, Bp, partial);
  beta_g_k<<<(2 * NH * L_SEQ + 255) / 256, 256, 0, stream>>>(partial, A_log, dt_bias, beta, g_arr);

  conv_qk_k<<<dim3(32, 32, 2), 64, 0, stream>>>(projQKV, Wc, qh, ql, kh, kl);
  conv_v_k<<<dim3(32, 4, 2), 256, 0, stream>>>(projQKV, Wc, vn);

  p1_k<<<1024, 256, 0, stream>>>(kh, kl, qh, ql, g_arr, beta, Tg_h, Tg_l, Hg_h, Hg_l, KTg_h, KTg_l, coefG);
  p2_k<<<256, 256, 0, stream>>>(qh, ql, kh, kl, vn, projGate, Tg_h, Tg_l, Hg_h, Hg_l, KTg_h, KTg_l, coefG, out);
}

// Round 16
// 926.401 us; speedup vs baseline: 1.0951x; 1.0951x over previous
//
#include <hip/hip_runtime.h>
#include <hip/hip_bf16.h>
#include <hip/hip_fp16.h>
#include <math.h>

#define L_SEQ 2048
#define DM    2048
#define NH    16
#define DH    128
#define HVD   256
#define NPROJ 12320
#define QKVW  8192
#define GW    4128

#define NTILE_N 97
#define KSTEPS  64

typedef _Float16 v8h __attribute__((ext_vector_type(8)));
typedef float f32x4 __attribute__((ext_vector_type(4)));

__device__ __forceinline__ void gload_lds16(const void* g, void* l) {
  __builtin_amdgcn_global_load_lds((const __attribute__((address_space(1))) void*)g,
                                   (__attribute__((address_space(3))) void*)l, 16, 0, 0);
}

__device__ __forceinline__ void splitw(float x, unsigned short& h, unsigned short& l) {
  _Float16 hh = (_Float16)x;
  _Float16 ll = (_Float16)(x - (float)hh);
  h = *(unsigned short*)&hh;
  l = *(unsigned short*)&ll;
}
__device__ __forceinline__ float h2f(unsigned short u) {
  return (float)(*(_Float16*)&u);
}

#define MFMA3(acc, ah, al, bh_, bl_)                                          \
  acc = __builtin_amdgcn_mfma_f32_16x16x32_f16(ah, bh_, acc, 0, 0, 0);        \
  acc = __builtin_amdgcn_mfma_f32_16x16x32_f16(ah, bl_, acc, 0, 0, 0);        \
  acc = __builtin_amdgcn_mfma_f32_16x16x32_f16(al, bh_, acc, 0, 0, 0);

// ---------------- pack A: hidden(4096x2048) f32 -> fp16 hi/lo, x16 ----------------
__global__ __launch_bounds__(256) void pack_A_k(const float* __restrict__ H, _Float16* __restrict__ Ap) {
  const int mtile = blockIdx.x >> 6, kstep = blockIdx.x & 63;
  const size_t base = (size_t)blockIdx.x * 2 * 4096;
#pragma unroll
  for (int it = 0; it < 2; ++it) {
    int s = threadIdx.x + it * 256;
    int g = s >> 7, r = s & 127;
    const float* src = H + ((size_t)(mtile * 128 + r)) * 2048 + kstep * 32 + g * 8;
    float4 x0 = *(const float4*)src;
    float4 x1 = *(const float4*)(src + 4);
    float xs[8] = {x0.x, x0.y, x0.z, x0.w, x1.x, x1.y, x1.z, x1.w};
    v8h hi, lo;
#pragma unroll
    for (int j = 0; j < 8; ++j) {
      float v = xs[j] * 16.f;
      _Float16 h = (_Float16)v;
      hi[j] = h;
      lo[j] = (_Float16)(v - (float)h);
    }
    *(v8h*)(Ap + base + g * 1024 + r * 8) = hi;
    *(v8h*)(Ap + base + 4096 + g * 1024 + r * 8) = lo;
  }
}

// ---------------- pack B: W(2048x12320) f32 -> fp16 hi/lo, x1024 ----------------
__global__ __launch_bounds__(256) void pack_B_k(const float* __restrict__ W, _Float16* __restrict__ Bp) {
  const int ntile = blockIdx.x >> 6, kstep = blockIdx.x & 63;
  const size_t base = (size_t)blockIdx.x * 2 * 4096;
#pragma unroll
  for (int it = 0; it < 2; ++it) {
    int s = threadIdx.x + it * 256;
    int g = s >> 7, col = s & 127;
    int n = ntile * 128 + col;
    v8h hi, lo;
#pragma unroll
    for (int j = 0; j < 8; ++j) {
      int k = kstep * 32 + g * 8 + j;
      float v = (n < NPROJ) ? W[(size_t)k * NPROJ + n] * 1024.f : 0.f;
      _Float16 h = (_Float16)v;
      hi[j] = h;
      lo[j] = (_Float16)(v - (float)h);
    }
    *(v8h*)(Bp + base + g * 1024 + col * 8) = hi;
    *(v8h*)(Bp + base + 4096 + g * 1024 + col * 8) = lo;
  }
}

// ---------------- 256x256 split-fp16 MFMA GEMM: 8 waves, 1 barrier/K-step ----------------
__global__ __launch_bounds__(512, 2) void gemm256_k(const _Float16* __restrict__ Ap,
                                                    const _Float16* __restrict__ Bp,
                                                    float* __restrict__ Cq,
                                                    float* __restrict__ Cg) {
  __shared__ _Float16 lds[2][32768];
  const int tid = threadIdx.x;
  const int supM = blockIdx.x & 15;
  const int supN = blockIdx.x >> 4;          // 0..47
  const int w = tid >> 6, lane = tid & 63;
  const int wm = w >> 2, wn = w & 3;
  const int lr = lane & 15, g16 = lane >> 4;

  f32x4 acc[8][4];
#pragma unroll
  for (int i = 0; i < 8; ++i)
#pragma unroll
    for (int j = 0; j < 4; ++j) acc[i][j] = (f32x4){0.f, 0.f, 0.f, 0.f};

  const size_t Ab0 = (size_t)(2 * supM) * KSTEPS * 8192;
  const size_t Ab1 = Ab0 + (size_t)KSTEPS * 8192;
  const size_t Bb0 = (size_t)(2 * supN) * KSTEPS * 8192;
  const size_t Bb1 = Bb0 + (size_t)KSTEPS * 8192;
  const int so = tid * 8;

#define STG(KS, BUF)                                                           \
  {                                                                            \
    const size_t ko = (size_t)(KS) * 8192;                                     \
    gload_lds16(Ap + Ab0 + ko + so,        &lds[BUF][so]);                     \
    gload_lds16(Ap + Ab0 + ko + so + 4096, &lds[BUF][so + 4096]);              \
    gload_lds16(Ap + Ab1 + ko + so,        &lds[BUF][8192 + so]);              \
    gload_lds16(Ap + Ab1 + ko + so + 4096, &lds[BUF][8192 + so + 4096]);       \
    gload_lds16(Bp + Bb0 + ko + so,        &lds[BUF][16384 + so]);             \
    gload_lds16(Bp + Bb0 + ko + so + 4096, &lds[BUF][16384 + so + 4096]);      \
    gload_lds16(Bp + Bb1 + ko + so,        &lds[BUF][24576 + so]);             \
    gload_lds16(Bp + Bb1 + ko + so + 4096, &lds[BUF][24576 + so + 4096]);      \
  }

  STG(0, 0);
  asm volatile("s_waitcnt vmcnt(0)" ::: "memory");
  __builtin_amdgcn_sched_barrier(0);
  __builtin_amdgcn_s_barrier();
  __builtin_amdgcn_sched_barrier(0);

  const int aoffB = wm * 8192 + lr * 8 + g16 * 1024;
  const int boffB = 16384 + (wn >> 1) * 8192 + ((wn & 1) * 64 + lr) * 8 + g16 * 1024;

  for (int kstep = 0; kstep < KSTEPS; ++kstep) {
    const int p = kstep & 1;
    if (kstep + 1 < KSTEPS) STG(kstep + 1, p ^ 1);

    v8h ah[8], al[8];
#pragma unroll
    for (int mb = 0; mb < 8; ++mb) {
      ah[mb] = *(const v8h*)&lds[p][aoffB + mb * 128];
      al[mb] = *(const v8h*)&lds[p][aoffB + mb * 128 + 4096];
    }
#pragma unroll
    for (int nt = 0; nt < 4; ++nt) {
      v8h bh = *(const v8h*)&lds[p][boffB + nt * 128];
      v8h bl = *(const v8h*)&lds[p][boffB + nt * 128 + 4096];
#pragma unroll
      for (int mb = 0; mb < 8; ++mb) {
        MFMA3(acc[mb][nt], ah[mb], al[mb], bh, bl);
      }
    }
    asm volatile("s_waitcnt vmcnt(0)" ::: "memory");
    __builtin_amdgcn_sched_barrier(0);
    __builtin_amdgcn_s_barrier();
    __builtin_amdgcn_sched_barrier(0);
  }
#undef STG

  const float sc = 1.f / 16384.f;
#pragma unroll
  for (int mb = 0; mb < 8; ++mb) {
#pragma unroll
    for (int nt = 0; nt < 4; ++nt) {
      int col = supN * 256 + wn * 64 + nt * 16 + lr;
#pragma unroll
      for (int r = 0; r < 4; ++r) {
        int row = supM * 256 + wm * 128 + mb * 16 + g16 * 4 + r;
        float v = acc[mb][nt][r] * sc;
        if (col < QKVW) Cq[(size_t)row * QKVW + col] = v;
        else            Cg[(size_t)row * GW + (col - QKVW)] = v;
      }
    }
  }
}

// ---------------- tail: b/A columns (ntile 96, first 32 cols) split-K partials ----------------
__global__ __launch_bounds__(256) void tail_k(const _Float16* __restrict__ Ap,
                                              const _Float16* __restrict__ Bp,
                                              float* __restrict__ partial) {
  __shared__ _Float16 lds[16384];
  const int bid = blockIdx.x;
  const int kseg = bid >> 5, mtile = bid & 31;
  const int tid = threadIdx.x;
  const int wid = tid >> 6, lane = tid & 63, lr = lane & 15, g16 = lane >> 4;

  f32x4 acc[2][2];
#pragma unroll
  for (int i = 0; i < 2; ++i)
#pragma unroll
    for (int j = 0; j < 2; ++j) acc[i][j] = (f32x4){0.f, 0.f, 0.f, 0.f};

  const _Float16* Asrc = Ap + ((size_t)(mtile * KSTEPS) * 2) * 4096 + tid * 8;
  const _Float16* Bsrc = Bp + ((size_t)(96 * KSTEPS) * 2) * 4096 + tid * 8;

  for (int ks = kseg * 16; ks < kseg * 16 + 16; ++ks) {
    __syncthreads();
#pragma unroll
    for (int r = 0; r < 4; ++r) {
      gload_lds16(Asrc + (size_t)ks * 8192 + r * 2048, &lds[r * 2048 + tid * 8]);
      gload_lds16(Bsrc + (size_t)ks * 8192 + r * 2048, &lds[8192 + r * 2048 + tid * 8]);
    }
    __syncthreads();
    const int abase = g16 * 1024;
#pragma unroll
    for (int fm = 0; fm < 2; ++fm) {
      int row = wid * 32 + fm * 16 + lr;
      v8h ah = *(const v8h*)&lds[abase + row * 8];
      v8h al = *(const v8h*)&lds[4096 + abase + row * 8];
#pragma unroll
      for (int fn = 0; fn < 2; ++fn) {
        int col = fn * 16 + lr;
        v8h bh = *(const v8h*)&lds[8192 + abase + col * 8];
        v8h bl = *(const v8h*)&lds[12288 + abase + col * 8];
        MFMA3(acc[fm][fn], ah, al, bh, bl);
      }
    }
  }

  const float sc = 1.f / 16384.f;
#pragma unroll
  for (int fm = 0; fm < 2; ++fm)
#pragma unroll
    for (int fn = 0; fn < 2; ++fn) {
      int col = fn * 16 + lr;
#pragma unroll
      for (int r = 0; r < 4; ++r) {
        int row = mtile * 128 + wid * 32 + fm * 16 + g16 * 4 + r;
        partial[((size_t)kseg * 4096 + row) * 32 + col] = acc[fm][fn][r] * sc;
      }
    }
}

// ------------- conv+silu+l2norm for q/k -> PRE-SPLIT fp16 hi/lo, pre-swizzled table layout -------------
__global__ __launch_bounds__(64) void conv_qk_k(
    const float* __restrict__ projQKV, const float* __restrict__ Wc,
    _Float16* __restrict__ qh, _Float16* __restrict__ ql,
    _Float16* __restrict__ kh, _Float16* __restrict__ kl)
{
  const int b = blockIdx.z, hg = blockIdx.y, tc = blockIdx.x;
  const int lane = threadIdx.x;
  const int ch = hg * 128 + lane * 2;
  float4 Wa = *(const float4*)(Wc + (size_t)ch * 4);
  float4 Wb = *(const float4*)(Wc + (size_t)ch * 4 + 4);
  const int t0 = tc * 64;
  const float* P = projQKV + (size_t)b * L_SEQ * QKVW + ch;
  float2 w0 = make_float2(0.f, 0.f), w1 = w0, w2 = w0;
  if (t0 >= 3) w0 = *(const float2*)(P + (size_t)(t0 - 3) * QKVW);
  if (t0 >= 2) w1 = *(const float2*)(P + (size_t)(t0 - 2) * QKVW);
  if (t0 >= 1) w2 = *(const float2*)(P + (size_t)(t0 - 1) * QKVW);
  const bool isq = hg < 16;
  const int h = isq ? hg : hg - 16;
  _Float16* dh = (isq ? qh : kh) + (((size_t)b * NH + h) * L_SEQ) * 128;
  _Float16* dl = (isq ? ql : kl) + (((size_t)b * NH + h) * L_SEQ) * 128;
  const float sc = (isq ? 0.08838834764831845f : 1.f) * 1024.f;
  for (int t = t0; t < t0 + 64; ++t) {
    float2 x = *(const float2*)(P + (size_t)t * QKVW);
    float y0 = w0.x * Wa.x + w1.x * Wa.y + w2.x * Wa.z + x.x * Wa.w;
    float y1 = w0.y * Wb.x + w1.y * Wb.y + w2.y * Wb.z + x.y * Wb.w;
    w0 = w1; w1 = w2; w2 = x;
    y0 = y0 / (1.f + expf(-y0));
    y1 = y1 / (1.f + expf(-y1));
    float ss = y0 * y0 + y1 * y1;
#pragma unroll
    for (int off = 1; off < 64; off <<= 1) ss += __shfl_xor(ss, off);
    float nrm = sc / sqrtf(ss + 1e-6f);
    unsigned short h0, l0, h1, l1;
    splitw(y0 * nrm, h0, l0);
    splitw(y1 * nrm, h1, l1);
    int idx = t * 128 + ((lane * 2) ^ ((t & 7) << 3));
    *(unsigned int*)&dh[idx] = (unsigned int)h0 | ((unsigned int)h1 << 16);
    *(unsigned int*)&dl[idx] = (unsigned int)l0 | ((unsigned int)l1 << 16);
  }
}

// ------------- conv+silu for v: elementwise, float4 per thread -------------
__global__ __launch_bounds__(256) void conv_v_k(
    const float* __restrict__ projQKV, const float* __restrict__ Wc,
    float* __restrict__ vn)
{
  const int b = blockIdx.z, cg = blockIdx.y, tc = blockIdx.x;
  const int vc = (cg * 256 + threadIdx.x) * 4;
  const int ch = 4096 + vc;
  float4 Wv0 = *(const float4*)(Wc + (size_t)ch * 4);
  float4 Wv1 = *(const float4*)(Wc + (size_t)ch * 4 + 4);
  float4 Wv2 = *(const float4*)(Wc + (size_t)ch * 4 + 8);
  float4 Wv3 = *(const float4*)(Wc + (size_t)ch * 4 + 12);
  const int t0 = tc * 64;
  const float* P = projQKV + (size_t)b * L_SEQ * QKVW + ch;
  float4 w0 = make_float4(0.f, 0.f, 0.f, 0.f), w1 = w0, w2 = w0;
  if (t0 >= 3) w0 = *(const float4*)(P + (size_t)(t0 - 3) * QKVW);
  if (t0 >= 2) w1 = *(const float4*)(P + (size_t)(t0 - 2) * QKVW);
  if (t0 >= 1) w2 = *(const float4*)(P + (size_t)(t0 - 1) * QKVW);
  const int h = vc >> 8, vcol = vc & 255;
  float* dst = vn + (((size_t)b * NH + h) * L_SEQ) * HVD + vcol;
  for (int t = t0; t < t0 + 64; ++t) {
    float4 x = *(const float4*)(P + (size_t)t * QKVW);
    float4 y;
    y.x = w0.x * Wv0.x + w1.x * Wv0.y + w2.x * Wv0.z + x.x * Wv0.w;
    y.y = w0.y * Wv1.x + w1.y * Wv1.y + w2.y * Wv1.z + x.y * Wv1.w;
    y.z = w0.z * Wv2.x + w1.z * Wv2.y + w2.z * Wv2.z + x.z * Wv2.w;
    y.w = w0.w * Wv3.x + w1.w * Wv3.y + w2.w * Wv3.z + x.w * Wv3.w;
    w0 = w1; w1 = w2; w2 = x;
    y.x = y.x / (1.f + expf(-y.x));
    y.y = y.y / (1.f + expf(-y.y));
    y.z = y.z / (1.f + expf(-y.z));
    y.w = y.w / (1.f + expf(-y.w));
    *(float4*)(dst + (size_t)t * HVD) = y;
  }
}

// ------------- beta/g from split-K partials -------------
__global__ __launch_bounds__(256) void beta_g_k(
    const float* __restrict__ partial, const float* __restrict__ A_log,
    const float* __restrict__ dt_bias, float* __restrict__ beta, float* __restrict__ g_out)
{
  int idx = blockIdx.x * 256 + threadIdx.x;
  if (idx >= 2 * NH * L_SEQ) return;
  int t = idx & (L_SEQ - 1);
  int h = (idx >> 11) & (NH - 1);
  int b = idx >> 15;
  size_t row = (size_t)(b * L_SEQ + t);
  float bv = 0.f, av = 0.f;
#pragma unroll
  for (int s = 0; s < 4; ++s) {
    bv += partial[((size_t)s * 4096 + row) * 32 + h];
    av += partial[((size_t)s * 4096 + row) * 32 + 16 + h];
  }
  float be = 1.f / (1.f + expf(-bv));
  float xx = av + dt_bias[h];
  float sp = (xx > 20.f) ? xx : log1pf(expf(xx));
  float g = -expf(A_log[h]) * sp;
  beta[idx] = be;
  g_out[idx] = g;
}

// ------------- Phase 1 (fused): T=(I+A)^-1, Hq, KT, coef — gload-staged pre-split q/k -------------
__global__ __launch_bounds__(256) void p1_k(
    const _Float16* __restrict__ kh_g, const _Float16* __restrict__ kl_g,
    const _Float16* __restrict__ qh_g, const _Float16* __restrict__ ql_g,
    const float* __restrict__ g_arr, const float* __restrict__ beta_arr,
    _Float16* __restrict__ Tg_h, _Float16* __restrict__ Tg_l,
    _Float16* __restrict__ Hg_h, _Float16* __restrict__ Hg_l,
    _Float16* __restrict__ KTg_h, _Float16* __restrict__ KTg_l,
    float* __restrict__ coefG)
{
  __shared__ _Float16 Kh[8192], Kl[8192];
  __shared__ _Float16 QS[16384];
  __shared__ float lc[64], be[64], kw[64];
  _Float16* Qh = QS;
  _Float16* Ql = QS + 8192;
  float* Am = (float*)QS;
  float* Tm = Am + 4096;
  const int cid = blockIdx.x, bh = cid >> 5, ch = cid & 31, t0 = ch * 64;
  const int tid = threadIdx.x, w = tid >> 6, lane = tid & 63, lr = lane & 15, g16 = lane >> 4;

  const size_t gb = ((size_t)bh * 2048 + t0) * 128;
#pragma unroll
  for (int l = 0; l < 4; ++l) {
    int i = (tid + l * 256) * 8;
    gload_lds16(kh_g + gb + i, &Kh[i]);
    gload_lds16(kl_g + gb + i, &Kl[i]);
    gload_lds16(qh_g + gb + i, &Qh[i]);
    gload_lds16(ql_g + gb + i, &Ql[i]);
  }
  if (tid < 64) {
    float x = g_arr[(size_t)bh * 2048 + t0 + tid];
#pragma unroll
    for (int off = 1; off < 64; off <<= 1) { float y = __shfl_up(x, off); if (tid >= off) x += y; }
    lc[tid] = x;
    float x63 = __shfl(x, 63);
    float b_ = beta_arr[(size_t)bh * 2048 + t0 + tid];
    be[tid] = b_;
    kw[tid] = expf(x63 - x);
    float ca = expf(x);
    coefG[(size_t)cid * 192 + tid] = ca;
    coefG[(size_t)cid * 192 + 64 + tid] = b_;
    coefG[(size_t)cid * 192 + 128 + tid] = b_ * ca;
  }
  __syncthreads();
  const float ds20 = 1.f / 1048576.f;
  const int arow = w * 16 + lr, swa = (arow & 7) << 3;
  f32x4 gacc[4];
  for (int nt = 0; nt < 4; ++nt) {
    f32x4 acc = (f32x4){0.f, 0.f, 0.f, 0.f};
    int nrow = nt * 16 + lr, swn = (nrow & 7) << 3;
#pragma unroll
    for (int ks = 0; ks < 4; ++ks) {
      int c = ks * 32 + g16 * 8;
      v8h ah = *(const v8h*)&Kh[arow * 128 + (c ^ swa)];
      v8h al = *(const v8h*)&Kl[arow * 128 + (c ^ swa)];
      v8h bhh = *(const v8h*)&Kh[nrow * 128 + (c ^ swn)];
      v8h bll = *(const v8h*)&Kl[nrow * 128 + (c ^ swn)];
      MFMA3(acc, ah, al, bhh, bll);
    }
    gacc[nt] = acc;
  }
  for (int nt = 0; nt < 4; ++nt) {
    f32x4 acc = (f32x4){0.f, 0.f, 0.f, 0.f};
    int nrow = nt * 16 + lr, swn = (nrow & 7) << 3;
#pragma unroll
    for (int ks = 0; ks < 4; ++ks) {
      int c = ks * 32 + g16 * 8;
      v8h ah = *(const v8h*)&Qh[arow * 128 + (c ^ swa)];
      v8h al = *(const v8h*)&Ql[arow * 128 + (c ^ swa)];
      v8h bhh = *(const v8h*)&Kh[nrow * 128 + (c ^ swn)];
      v8h bll = *(const v8h*)&Kl[nrow * 128 + (c ^ swn)];
      MFMA3(acc, ah, al, bhh, bll);
    }
    int s_ = nt * 16 + lr;
#pragma unroll
    for (int r = 0; r < 4; ++r) {
      int t = w * 16 + g16 * 4 + r;
      float hv = (s_ <= t) ? acc[r] * ds20 * expf(lc[t] - lc[s_]) : 0.f;
      unsigned short hh, ll; splitw(hv * 16384.f, hh, ll);
      size_t go = (size_t)cid * 4096 + t * 64 + (s_ ^ ((t & 7) << 3));
      *(unsigned short*)&Hg_h[go] = hh;
      *(unsigned short*)&Hg_l[go] = ll;
    }
  }
  __syncthreads();
  for (int nt = 0; nt < 4; ++nt) {
    int s_ = nt * 16 + lr;
#pragma unroll
    for (int r = 0; r < 4; ++r) {
      int t = w * 16 + g16 * 4 + r;
      float av = (s_ < t) ? gacc[nt][r] * ds20 * be[t] * expf(lc[t] - lc[s_]) : 0.f;
      Am[t * 64 + s_] = av;
    }
  }
#pragma unroll
  for (int l = 0; l < 16; ++l) { int s2 = tid + l * 256; Tm[s2] = ((s2 >> 6) == (s2 & 63)) ? 1.f : 0.f; }
  for (int s = tid; s < 8192; s += 256) {
    int feat = s >> 6, t = s & 63;
    int ki = t * 128 + (feat ^ ((t & 7) << 3));
    float kvv = ((float)Kh[ki] + (float)Kl[ki]) * kw[t];
    unsigned short hh, ll; splitw(kvv, hh, ll);
    size_t go = (size_t)cid * 8192 + feat * 64 + (t ^ ((feat & 7) << 3));
    *(unsigned short*)&KTg_h[go] = hh;
    *(unsigned short*)&KTg_l[go] = ll;
  }
  __syncthreads();
  if (w == 0) {
    int j = lane;
    for (int t = 1; t < 64; ++t) {
      float sum = 0.f;
      for (int s = 0; s < t; ++s) sum = fmaf(Am[t * 64 + s], Tm[s * 64 + j], sum);
      Tm[t * 64 + j] = ((j == t) ? 1.f : 0.f) - sum;
    }
  }
  __syncthreads();
#pragma unroll
  for (int l = 0; l < 16; ++l) {
    int s2 = tid + l * 256;
    int t = s2 >> 6, sc_ = s2 & 63;
    unsigned short hh, ll; splitw(Tm[s2] * 256.f, hh, ll);
    size_t go = (size_t)cid * 4096 + t * 64 + (sc_ ^ ((t & 7) << 3));
    *(unsigned short*)&Tg_h[go] = hh;
    *(unsigned short*)&Tg_l[go] = ll;
  }
}

// ------------- Phase 2: sequential chunk scan, VW=32, 256 blocks, 5 barriers/chunk (R14-exact) -------------
__global__ __launch_bounds__(256) void p2_k(
    const _Float16* __restrict__ qh_g, const _Float16* __restrict__ ql_g,
    const _Float16* __restrict__ kh_g, const _Float16* __restrict__ kl_g,
    const float* __restrict__ vn, const float* __restrict__ projGate,
    const _Float16* __restrict__ Tg_h, const _Float16* __restrict__ Tg_l,
    const _Float16* __restrict__ Hg_h, const _Float16* __restrict__ Hg_l,
    const _Float16* __restrict__ KTg_h, const _Float16* __restrict__ KTg_l,
    const float* __restrict__ coefG, float* __restrict__ out)
{
  __shared__ _Float16 St_h[4096], St_l[4096];
  __shared__ _Float16 KQ0[8192], KQ1[8192];
  __shared__ _Float16 KK0[8192], KK1[8192];
  __shared__ _Float16 KTs_h[8192], KTs_l[8192];
  __shared__ _Float16 Ts_h[4096], Ts_l[4096];
  __shared__ _Float16 Hs_h[4096], Hs_l[4096];
  __shared__ float cf[192];

  const int blk = blockIdx.x;
  const int vb = blk >> 5, bh = blk & 31;
  const int b = bh >> 4, h = bh & 15, v0 = vb * 32;
  const int tid = threadIdx.x, w = tid >> 6, lane = tid & 63, lr = lane & 15, g16 = lane >> 4;

  _Float16* BT_h = &KQ0[0];
  _Float16* BT_l = &KQ0[4096];
  _Float16* UT_h = &KQ1[0];
  _Float16* UT_l = &KQ1[4096];

#pragma unroll
  for (int l = 0; l < 8; ++l) { ((unsigned int*)St_h)[tid + l * 256] = 0u; }
#pragma unroll
  for (int l = 0; l < 8; ++l) { ((unsigned int*)St_l)[tid + l * 256] = 0u; }

  const float* gp = projGate + ((size_t)b * 2048) * GW + h * 256 + v0;
  const float i2_16 = 1.f / 65536.f;
  const float i2_20 = 1.f / 1048576.f;
  const float uscale = 1.f / 256.f;
  const float sscale = 64.f / 65536.f;

  for (int ch = 0; ch < 32; ++ch) {
    const int cid = bh * 32 + ch, t0 = ch * 64;
    {
      const _Float16* th = Tg_h + (size_t)cid * 4096;
      const _Float16* tl = Tg_l + (size_t)cid * 4096;
      const _Float16* hh = Hg_h + (size_t)cid * 4096;
      const _Float16* hl = Hg_l + (size_t)cid * 4096;
      const _Float16* kth = KTg_h + (size_t)cid * 8192;
      const _Float16* ktl = KTg_l + (size_t)cid * 8192;
      const size_t gb = ((size_t)bh * 2048 + t0) * 128;
#pragma unroll
      for (int l = 0; l < 2; ++l) {
        int i = (tid + l * 256) * 8;
        gload_lds16(th + i, &Ts_h[i]);
        gload_lds16(tl + i, &Ts_l[i]);
        gload_lds16(hh + i, &Hs_h[i]);
        gload_lds16(hl + i, &Hs_l[i]);
      }
#pragma unroll
      for (int l = 0; l < 4; ++l) {
        int i = (tid + l * 256) * 8;
        gload_lds16(kth + i, &KTs_h[i]);
        gload_lds16(ktl + i, &KTs_l[i]);
        gload_lds16(qh_g + gb + i, &KQ0[i]);
        gload_lds16(ql_g + gb + i, &KQ1[i]);
        gload_lds16(kh_g + gb + i, &KK0[i]);
        gload_lds16(kl_g + gb + i, &KK1[i]);
      }
      if (tid < 48) gload_lds16(coefG + (size_t)cid * 192 + tid * 4, &cf[tid * 4]);
    }
    float Vv[2][4];
#pragma unroll
    for (int nt = 0; nt < 2; ++nt)
#pragma unroll
      for (int r = 0; r < 4; ++r)
        Vv[nt][r] = vn[((size_t)bh * 2048 + t0 + w * 16 + g16 * 4 + r) * 256 + v0 + nt * 16 + lr];
    __syncthreads();
    const float cc = cf[63];
    const int arow = w * 16 + lr, swa = (arow & 7) << 3;
    f32x4 Oacc[2];
    {
      for (int nt = 0; nt < 2; ++nt) {
        f32x4 acc = (f32x4){0.f, 0.f, 0.f, 0.f};
        const int n = nt * 16 + lr, swn = (n & 7) << 3;
#pragma unroll
        for (int ks = 0; ks < 4; ++ks) {
          int c = ks * 32 + g16 * 8;
          v8h ah = *(const v8h*)&KQ0[arow * 128 + (c ^ swa)];
          v8h al = *(const v8h*)&KQ1[arow * 128 + (c ^ swa)];
          v8h bhh = *(const v8h*)&St_h[n * 128 + (c ^ swn)];
          v8h bll = *(const v8h*)&St_l[n * 128 + (c ^ swn)];
          MFMA3(acc, ah, al, bhh, bll);
        }
        Oacc[nt] = acc;
      }
      float4 cav = *(float4*)&cf[w * 16 + g16 * 4];
#pragma unroll
      for (int nt = 0; nt < 2; ++nt) {
        Oacc[nt][0] *= cav.x * 16.f; Oacc[nt][1] *= cav.y * 16.f;
        Oacc[nt][2] *= cav.z * 16.f; Oacc[nt][3] *= cav.w * 16.f;
      }
    }
    ushort4 pBh[2], pBl[2];
    {
      float4 cb1v = *(float4*)&cf[64 + w * 16 + g16 * 4];
      float4 cb2v = *(float4*)&cf[128 + w * 16 + g16 * 4];
      for (int nt = 0; nt < 2; ++nt) {
        f32x4 acc = (f32x4){0.f, 0.f, 0.f, 0.f};
        const int n = nt * 16 + lr, swn = (n & 7) << 3;
#pragma unroll
        for (int ks = 0; ks < 4; ++ks) {
          int c = ks * 32 + g16 * 8;
          v8h ah = *(const v8h*)&KK0[arow * 128 + (c ^ swa)];
          v8h al = *(const v8h*)&KK1[arow * 128 + (c ^ swa)];
          v8h bhh = *(const v8h*)&St_h[n * 128 + (c ^ swn)];
          v8h bll = *(const v8h*)&St_l[n * 128 + (c ^ swn)];
          MFMA3(acc, ah, al, bhh, bll);
        }
        float cb1a[4] = {cb1v.x, cb1v.y, cb1v.z, cb1v.w};
        float cb2a[4] = {cb2v.x, cb2v.y, cb2v.z, cb2v.w};
        unsigned short* ph = (unsigned short*)&pBh[nt];
        unsigned short* pl = (unsigned short*)&pBl[nt];
#pragma unroll
        for (int r = 0; r < 4; ++r) {
          float kv = acc[r] * i2_16;
          float Bv = cb1a[r] * Vv[nt][r] - cb2a[r] * kv;
          splitw(Bv * 64.f, ph[r], pl[r]);
        }
      }
    }
    __syncthreads();
    {
      const int tb = w * 16 + g16 * 4;
      for (int nt = 0; nt < 2; ++nt) {
        const int n = nt * 16 + lr, swn = (n & 7) << 3;
        int ad = n * 64 + (tb ^ swn);
        *(ushort4*)&BT_h[ad] = pBh[nt];
        *(ushort4*)&BT_l[ad] = pBl[nt];
      }
    }
    __syncthreads();
    {
      const int tb = w * 16 + g16 * 4;
      for (int nt = 0; nt < 2; ++nt) {
        f32x4 acc = (f32x4){0.f, 0.f, 0.f, 0.f};
        const int n = nt * 16 + lr, swn = (n & 7) << 3;
#pragma unroll
        for (int ks = 0; ks < 2; ++ks) {
          int c = ks * 32 + g16 * 8;
          v8h ah = *(const v8h*)&Ts_h[arow * 64 + (c ^ swa)];
          v8h al = *(const v8h*)&Ts_l[arow * 64 + (c ^ swa)];
          v8h bhh = *(const v8h*)&BT_h[n * 64 + (c ^ swn)];
          v8h bll = *(const v8h*)&BT_l[n * 64 + (c ^ swn)];
          MFMA3(acc, ah, al, bhh, bll);
        }
        ushort4 H, L;
        unsigned short* ph = (unsigned short*)&H;
        unsigned short* pl = (unsigned short*)&L;
#pragma unroll
        for (int r = 0; r < 4; ++r) splitw(acc[r] * uscale, ph[r], pl[r]);
        int ad = n * 64 + (tb ^ swn);
        *(ushort4*)&UT_h[ad] = H;
        *(ushort4*)&UT_l[ad] = L;
      }
    }
    __syncthreads();
    {
      for (int nt = 0; nt < 2; ++nt) {
        const int n = nt * 16 + lr, swn = (n & 7) << 3;
#pragma unroll
        for (int ks = 0; ks < 2; ++ks) {
          int c = ks * 32 + g16 * 8;
          v8h ah = *(const v8h*)&Hs_h[arow * 64 + (c ^ swa)];
          v8h al = *(const v8h*)&Hs_l[arow * 64 + (c ^ swa)];
          v8h bhh = *(const v8h*)&UT_h[n * 64 + (c ^ swn)];
          v8h bll = *(const v8h*)&UT_l[n * 64 + (c ^ swn)];
          MFMA3(Oacc[nt], ah, al, bhh, bll);
        }
      }
      for (int nt = 0; nt < 2; ++nt) {
        const int n = nt * 16 + lr;
#pragma unroll
        for (int r = 0; r < 4; ++r) {
          int t = t0 + w * 16 + g16 * 4 + r;
          float Ov = Oacc[nt][r] * i2_20;
          float gv = gp[(size_t)t * GW + n];
          out[((size_t)b * 2048 + t) * 4096 + h * 256 + v0 + n] = Ov * (gv / (1.f + expf(-gv)));
        }
      }
      const float cc1024 = cc * 1024.f;
#pragma unroll
      for (int m2 = w * 2; m2 < w * 2 + 2; ++m2) {
        const int ar2 = m2 * 16 + lr, swa2 = (ar2 & 7) << 3;
        const int fb = m2 * 16 + g16 * 4;
        for (int nt = 0; nt < 2; ++nt) {
          const int n = nt * 16 + lr, swn = (n & 7) << 3;
          int sad = n * 128 + (fb ^ swn);
          ushort4 sh4 = *(ushort4*)&St_h[sad];
          ushort4 sl4 = *(ushort4*)&St_l[sad];
          f32x4 acc;
          acc[0] = cc1024 * (h2f(sh4.x) + h2f(sl4.x));
          acc[1] = cc1024 * (h2f(sh4.y) + h2f(sl4.y));
          acc[2] = cc1024 * (h2f(sh4.z) + h2f(sl4.z));
          acc[3] = cc1024 * (h2f(sh4.w) + h2f(sl4.w));
#pragma unroll
          for (int ks = 0; ks < 2; ++ks) {
            int c = ks * 32 + g16 * 8;
            v8h ah = *(const v8h*)&KTs_h[ar2 * 64 + (c ^ swa2)];
            v8h al = *(const v8h*)&KTs_l[ar2 * 64 + (c ^ swa2)];
            v8h bhh = *(const v8h*)&UT_h[n * 64 + (c ^ swn)];
            v8h bll = *(const v8h*)&UT_l[n * 64 + (c ^ swn)];
            MFMA3(acc, ah, al, bhh, bll);
          }
          ushort4 H, L;
          unsigned short* ph = (unsigned short*)&H;
          unsigned short* pl = (unsigned short*)&L;
#pragma unroll
          for (int r = 0; r < 4; ++r) splitw(acc[r] * sscale, ph[r], pl[r]);
          *(ushort4*)&St_h[sad] = H;
          *(ushort4*)&St_l[sad] = L;
        }
      }
    }
    __syncthreads();
  }
}

extern "C" void kernel_launch(void* const* d_in, const int* in_sizes, int n_in,
                              void* d_out, int out_size, void* d_ws, size_t ws_size,
                              hipStream_t stream) {
  const float* hidden  = (const float*)d_in[0];
  const float* W       = (const float*)d_in[1];
  const float* Wc      = (const float*)d_in[2];
  const float* A_log   = (const float*)d_in[3];
  const float* dt_bias = (const float*)d_in[4];
  float* out = (float*)d_out;

  char* ws = (char*)d_ws;
  _Float16* Ap = (_Float16*)ws;
  _Float16* Bp = (_Float16*)(ws + (size_t)33554432);
  float* partial = (float*)(ws + (size_t)33554432);        // dead Bp tiles 0-1; consumed by beta_g before conv
  _Float16* qh = (_Float16*)ws;
  _Float16* ql = (_Float16*)(ws + (size_t)16777216);
  _Float16* kh = (_Float16*)(ws + (size_t)33554432);
  _Float16* kl = (_Float16*)(ws + (size_t)50331648);
  float* vn    = (float*)(ws + (size_t)67108864);
  float* g_arr = (float*)(ws + (size_t)134217728);
  float* beta  = (float*)(ws + (size_t)134479872);
  float* projQKV = (float*)(ws + (size_t)135266304);
  char*  tb0 = ws + (size_t)135266304;
  _Float16* Tg_h  = (_Float16*)tb0;
  _Float16* Tg_l  = (_Float16*)(tb0 + (size_t)8388608);
  _Float16* Hg_h  = (_Float16*)(tb0 + (size_t)16777216);
  _Float16* Hg_l  = (_Float16*)(tb0 + (size_t)25165824);
  _Float16* KTg_h = (_Float16*)(tb0 + (size_t)33554432);
  _Float16* KTg_l = (_Float16*)(tb0 + (size_t)50331648);
  float*    coefG = (float*)   (tb0 + (size_t)67108864);
  float* projGate = (float*)(ws + (size_t)269484032);

  pack_A_k<<<32 * KSTEPS, 256, 0, stream>>>(hidden, Ap);
  pack_B_k<<<NTILE_N * KSTEPS, 256, 0, stream>>>(W, Bp);
  gemm256_k<<<768, 512, 0, stream>>>(Ap, Bp, projQKV, projGate);
  tail_k<<<128, 256, 0, stream>>>(Ap, Bp, partial);
  beta_g_k<<<(2 * NH * L_SEQ + 255) / 256, 256, 0, stream>>>(partial, A_log, dt_bias, beta, g_arr);

  conv_qk_k<<<dim3(32, 32, 2), 64, 0, stream>>>(projQKV, Wc, qh, ql, kh, kl);
  conv_v_k<<<dim3(32, 4, 2), 256, 0, stream>>>(projQKV, Wc, vn);

  p1_k<<<1024, 256, 0, stream>>>(kh, kl, qh, ql, g_arr, beta, Tg_h, Tg_l, Hg_h, Hg_l, KTg_h, KTg_l, coefG);
  p2_k<<<256, 256, 0, stream>>>(qh, ql, kh, kl, vn, projGate, Tg_h, Tg_l, Hg_h, Hg_l, KTg_h, KTg_l, coefG, out);
}